// Round 6
// baseline (177.271 us; speedup 1.0000x reference)
//
#include <hip/hip_runtime.h>

// SFM recurrent model via MFMA: B=2048, T=60, D=6, H=64, F=10, O=1.
//
// R1-R3: VALU readlane-GEMV stuck at 183 us (readlane ~1/4 rate).
// R4: 5 GEMVs via mfma_16x16x32_bf16 split-bf16 -> 100 us.
// R5: pre-split bf16 hi/lo in LDS, conflict remap -> 83 us, but
//     MfmaUtil+VALUBusy = 51% -> ~1630 cyc/step of stall at 1 wave/SIMD
//     (exposed dep latency + serial barrier chain).
// R6: 512 blocks x 4 batches -> 2 blocks/CU. Independent barrier domains
//     slide past each other; MFMA & VALU pipes co-schedule (m114).
//     MFMA instr/CU doubles (pipe had 5x headroom); VALU/wave ~halves
//     (1 col/thread in pointwise).
//
// MFMA tile: m=batch (4 of 16, 4x mirror), n=hcol, K=96: rows 0..63 h@U,
// 64..69 x@W, 70 bias (A row 70 = 1.0). Wave g owns gate g; wave 3 also
// fre tile. C layout: n=lane&15, m=quad*4+reg (quad 0 holds batches 0..3).

#define BB 2048
#define TT 60
#define DD 6
#define HH 64
#define FF 10
#define NB 4     // batches per block

#define XS 968   // xsp per-batch stride in shorts (60*16 + 8 pad)
#define HS 72    // h split per-batch stride in shorts (144B, 16B-aligned)

typedef short bf16x8 __attribute__((ext_vector_type(8)));
typedef float f32x4  __attribute__((ext_vector_type(4)));

__device__ __forceinline__ unsigned short f2bf(float f) {
    union { float f; unsigned u; } v; v.f = f;
    unsigned r = v.u + 0x7fffu + ((v.u >> 16) & 1u);   // round-to-nearest-even
    return (unsigned short)(r >> 16);
}
__device__ __forceinline__ float bf2f(unsigned short b) {
    union { unsigned u; float f; } v; v.u = ((unsigned)b) << 16; return v.f;
}
__device__ __forceinline__ float hsig_f(float v) {
    return fminf(fmaxf(fmaf(v, 0.16666666666666666f, 0.5f), 0.0f), 1.0f);
}
__device__ __forceinline__ float tanh_f(float x) {
    float xc = fminf(fmaxf(x, -12.0f), 12.0f);
    float e  = __builtin_amdgcn_exp2f(xc * 2.8853900817779268f); // 2*log2(e)
    return (e - 1.0f) * __builtin_amdgcn_rcpf(e + 1.0f);
}
__device__ __forceinline__ float uni(float v) {
    return __int_as_float(__builtin_amdgcn_readfirstlane(__float_as_int(v)));
}
__device__ __forceinline__ void pinv(bf16x8& v) { asm volatile("" : "+v"(v)); }

__global__ __launch_bounds__(256, 2)
void sfm_kernel(
    const float* __restrict__ x,
    const float* __restrict__ W_i,  const float* __restrict__ U_i,  const float* __restrict__ b_i,
    const float* __restrict__ W_ste,const float* __restrict__ U_ste,const float* __restrict__ b_ste,
    const float* __restrict__ W_fre,const float* __restrict__ U_fre,const float* __restrict__ b_fre,
    const float* __restrict__ W_c,  const float* __restrict__ U_c,  const float* __restrict__ b_c,
    const float* __restrict__ W_o,  const float* __restrict__ U_o,  const float* __restrict__ b_o,
    const float* __restrict__ U_a,  const float* __restrict__ b_a,
    const float* __restrict__ W_p,  const float* __restrict__ b_p,
    float* __restrict__ out)
{
    const int tid  = threadIdx.x;
    const int lane = tid & 63;
    const int wave = tid >> 6;      // == gate id (0=i,1=ste,2=c,3=o)
    const int q    = lane >> 4;     // quad 0..3
    const int n16  = lane & 15;
    const int b0   = blockIdx.x * NB;

    __shared__ __align__(16) unsigned short xsp[NB * XS];   // presplit x
    __shared__ __align__(16) unsigned short hhi[NB * HS];   // h hi-bf16
    __shared__ __align__(16) unsigned short hlo[NB * HS];   // h lo-bf16
    __shared__ __align__(16) float zbuf[4 * 64 * NB];       // z[g][hcol][b]
    __shared__ __align__(16) float frebuf[16 * NB];         // zfre[f][b]
    __shared__ float red[4][NB];

    // ---- stage + pre-split x (one (b,s) record per thread) ----
    for (int item = tid; item < NB * TT; item += 256) {
        const float* xg = x + (size_t)b0 * (TT * DD) + item * DD;
        const int b = item / TT, s = item - b * TT;
        unsigned short* dst = &xsp[b * XS + s * 16];
        #pragma unroll
        for (int d = 0; d < DD; ++d) {
            const float v = xg[d];
            const unsigned short hb = f2bf(v);
            dst[d]     = hb;
            dst[8 + d] = f2bf(v - bf2f(hb));
        }
        dst[6] = 0x3F80; dst[7] = 0;   // bias row: 1.0 exact, lo = 0
        dst[14] = 0; dst[15] = 0;
    }
    for (int i = tid; i < NB * HS; i += 256) { hhi[i] = 0; hlo[i] = 0; }

    // ---- per-wave gate weights ----
    const float* Ug = (wave == 0) ? U_i : (wave == 1) ? U_ste : (wave == 2) ? U_c : U_o;
    const float* Wg = (wave == 0) ? W_i : (wave == 1) ? W_ste : (wave == 2) ? W_c : W_o;
    const float* bg = (wave == 0) ? b_i : (wave == 1) ? b_ste : (wave == 2) ? b_c : b_o;

    // ---- static B-frags: B[k][n], lane holds k = c*32 + q*8 + j, n = n16(+16t) ----
    bf16x8 Bh[5][3], Bl[5][3];
    #pragma unroll
    for (int t = 0; t < 5; ++t) {
        #pragma unroll
        for (int c = 0; c < 3; ++c) {
            #pragma unroll
            for (int j = 0; j < 8; ++j) {
                const int kv = c * 32 + q * 8 + j;   // 0..95 (71..95 zero rows)
                float v = 0.0f;
                if (t < 4) {
                    const int n = t * 16 + n16;
                    if      (kv < 64)  v = Ug[kv * HH + n];
                    else if (kv < 70)  v = Wg[(kv - 64) * HH + n];
                    else if (kv == 70) v = bg[n];
                } else if (wave == 3 && n16 < FF) {
                    if      (kv < 64)  v = U_fre[kv * FF + n16];
                    else if (kv < 70)  v = W_fre[(kv - 64) * FF + n16];
                    else if (kv == 70) v = b_fre[n16];
                }
                const unsigned short hb = f2bf(v);
                Bh[t][c][j] = (short)hb;
                Bl[t][c][j] = (short)f2bf(v - bf2f(hb));
            }
            pinv(Bh[t][c]); pinv(Bl[t][c]);
        }
    }

    // ---- pointwise mapping: batch pb = tid&3, col pc = tid>>2 (0..63) ----
    const int pb = tid & (NB - 1);
    const int pc = tid >> 2;
    const float bav = b_a[pc];
    const float wpv = W_p[pc];
    const float bpv = uni(b_p[0]);
    float uav[FF];
    #pragma unroll
    for (int f = 0; f < FF; ++f) uav[f] = uni(U_a[f]);

    // ---- rotation constants: cos/sin(2*pi*f/10), exact, period-10 reset ----
    const float CBt[FF] = { 1.0f,  0.8090169943749475f,  0.30901699437494745f,
                           -0.30901699437494745f, -0.8090169943749475f, -1.0f,
                           -0.8090169943749475f, -0.30901699437494745f,
                            0.30901699437494745f,  0.8090169943749475f };
    const float SBt[FF] = { 0.0f,  0.5877852522924731f,  0.9510565162951535f,
                            0.9510565162951535f,  0.5877852522924731f,  0.0f,
                           -0.5877852522924731f, -0.9510565162951535f,
                           -0.9510565162951535f, -0.5877852522924731f };

    float Sre[FF], Sim[FF], cs[FF], sn[FF];
    #pragma unroll
    for (int f = 0; f < FF; ++f) {
        Sre[f] = 0.0f; Sim[f] = 0.0f; cs[f] = CBt[f]; sn[f] = SBt[f];
    }
    float hv = 0.0f;

    __syncthreads();

    int sm = 0;
    for (int s = 0; s < TT; ++s) {
        // ---- A-frags: pure vector LDS reads of pre-split bf16 ----
        const int ab = n16 & (NB - 1);
        bf16x8 Ah[3], Al[3];
        #pragma unroll
        for (int c = 0; c < 2; ++c) {
            Ah[c] = *(const bf16x8*)&hhi[ab * HS + c * 32 + q * 8];
            Al[c] = *(const bf16x8*)&hlo[ab * HS + c * 32 + q * 8];
        }
        {
            const bf16x8 xvh = *(const bf16x8*)&xsp[ab * XS + s * 16];
            const bf16x8 xvl = *(const bf16x8*)&xsp[ab * XS + s * 16 + 8];
            const bf16x8 zf = {0, 0, 0, 0, 0, 0, 0, 0};
            Ah[2] = (q == 0) ? xvh : zf;
            Al[2] = (q == 0) ? xvl : zf;
        }

        // ---- MFMAs: z = (Ah+Al)(Bh+Bl), 3-term split ----
        f32x4 acc[5];
        #pragma unroll
        for (int t = 0; t < 5; ++t) {
            if (t < 4 || wave == 3) {
                f32x4 a = {0.0f, 0.0f, 0.0f, 0.0f};
                #pragma unroll
                for (int c = 0; c < 3; ++c) {
                    a = __builtin_amdgcn_mfma_f32_16x16x32_bf16(Al[c], Bh[t][c], a, 0, 0, 0);
                    a = __builtin_amdgcn_mfma_f32_16x16x32_bf16(Ah[c], Bl[t][c], a, 0, 0, 0);
                    a = __builtin_amdgcn_mfma_f32_16x16x32_bf16(Ah[c], Bh[t][c], a, 0, 0, 0);
                }
                acc[t] = a;
            }
        }

        // ---- write z to LDS (quad 0 regs 0..3 = batches 0..3) ----
        if (q == 0) {
            #pragma unroll
            for (int t = 0; t < 4; ++t)
                *(f32x4*)&zbuf[(wave * 64 + t * 16 + n16) * NB] = acc[t];
            if (wave == 3 && n16 < FF)
                *(f32x4*)&frebuf[n16 * NB] = acc[4];
        }
        __syncthreads();

        // ---- pointwise: batch pb, col pc ----
        const float zi = zbuf[(0 * 64 + pc) * NB + pb];
        const float zs = zbuf[(1 * 64 + pc) * NB + pb];
        const float zc = zbuf[(2 * 64 + pc) * NB + pb];
        const float zo = zbuf[(3 * 64 + pc) * NB + pb];
        float fr[FF];
        #pragma unroll
        for (int f = 0; f < FF; ++f) fr[f] = hsig_f(frebuf[f * NB + pb]);

        const float iv  = hsig_f(zi);
        const float stv = hsig_f(zs);
        const float ov  = hsig_f(zo);
        const float cv  = iv * tanh_f(zc);

        if (sm == 0) {
            #pragma unroll
            for (int f = 0; f < FF; ++f) { cs[f] = CBt[f]; sn[f] = SBt[f]; }
        }

        float aacc = bav;
        #pragma unroll
        for (int f = 0; f < FF; ++f) {
            const float fc = stv * fr[f];
            Sre[f] = fmaf(fc, Sre[f], cv * cs[f]);
            Sim[f] = fmaf(fc, Sim[f], cv * sn[f]);
            const float A = fmaf(Sim[f], Sim[f], Sre[f] * Sre[f]);
            aacc = fmaf(A, uav[f], aacc);
            const float cc = cs[f];
            cs[f] = fmaf(cc, CBt[f], -(sn[f] * SBt[f]));
            sn[f] = fmaf(cc, SBt[f],   sn[f] * CBt[f]);
        }
        hv = ov * tanh_f(aacc);

        // split h -> bf16 hi/lo, write to LDS (the ONLY conversion point)
        {
            const unsigned short hb = f2bf(hv);
            hhi[pb * HS + pc] = hb;
            hlo[pb * HS + pc] = f2bf(hv - bf2f(hb));
        }
        if (++sm == 10) sm = 0;
        __syncthreads();
    }

    // ---- output: out[b] = sum_col h*W_p + b_p ----
    // wave w, lane l: batch = l&3, col = w*16 + (l>>2).
    float val = hv * wpv;
    val += __shfl_xor(val, 4, 64);
    val += __shfl_xor(val, 8, 64);
    val += __shfl_xor(val, 16, 64);
    val += __shfl_xor(val, 32, 64);
    if (lane < NB) red[wave][lane] = val;   // lanes 0..3: batch = lane
    __syncthreads();
    if (tid < NB)
        out[b0 + tid] = red[0][tid] + red[1][tid] + red[2][tid] + red[3][tid] + bpv;
}

extern "C" void kernel_launch(void* const* d_in, const int* in_sizes, int n_in,
                              void* d_out, int out_size, void* d_ws, size_t ws_size,
                              hipStream_t stream) {
    (void)in_sizes; (void)n_in; (void)d_ws; (void)ws_size; (void)out_size;
    const float* x     = (const float*)d_in[0];
    const float* W_i   = (const float*)d_in[1];
    const float* U_i   = (const float*)d_in[2];
    const float* b_i   = (const float*)d_in[3];
    const float* W_ste = (const float*)d_in[4];
    const float* U_ste = (const float*)d_in[5];
    const float* b_ste = (const float*)d_in[6];
    const float* W_fre = (const float*)d_in[7];
    const float* U_fre = (const float*)d_in[8];
    const float* b_fre = (const float*)d_in[9];
    const float* W_c   = (const float*)d_in[10];
    const float* U_c   = (const float*)d_in[11];
    const float* b_c   = (const float*)d_in[12];
    const float* W_o   = (const float*)d_in[13];
    const float* U_o   = (const float*)d_in[14];
    const float* b_o   = (const float*)d_in[15];
    const float* U_a   = (const float*)d_in[16];
    const float* b_a   = (const float*)d_in[17];
    const float* W_p   = (const float*)d_in[18];
    const float* b_p   = (const float*)d_in[19];

    sfm_kernel<<<BB / NB, 256, 0, stream>>>(
        x, W_i, U_i, b_i, W_ste, U_ste, b_ste, W_fre, U_fre, b_fre,
        W_c, U_c, b_c, W_o, U_o, b_o, U_a, b_a, W_p, b_p, (float*)d_out);
}

// Round 7
// 166.850 us; speedup vs baseline: 1.0625x; 1.0625x over previous
//
#include <hip/hip_runtime.h>

// SFM recurrent model via MFMA: B=2048, T=60, D=6, H=64, F=10, O=1.
//
// R1-R3: VALU readlane-GEMV stuck at 183 us (readlane ~1/4 rate).
// R4: 5 GEMVs via mfma_16x16x32_bf16 split-bf16 -> 100 us.
// R5: pre-split bf16 hi/lo in LDS, conflict remap -> 83 us (1 blk/CU,
//     49% idle: no latency hiding at 1 wave/SIMD).
// R6: 512 blocks x 4 batches, 2 blk/CU -> 98 us. Overlap worked
//     (busy 51->74%) but MFMA/CU doubled AND MfmaUtil revealed ~15
//     cyc/MFMA: the 9-deep accumulator chains serialize (compiler
//     didn't interleave independent tiles).
// R7: (a) interleave MFMA accs (c,term outer; t inner) -> 4-5-way ILP,
//     (b) unroll step loop by 10: cos/sin rotation -> compile-time
//     constants (period 10), (c) hsig via fmed3.
//
// MFMA tile: m=batch (4 of 16, 4x mirror), n=hcol, K=96: rows 0..63 h@U,
// 64..69 x@W, 70 bias (A row 70 = 1.0). Wave g owns gate g; wave 3 also
// fre tile. C layout: n=lane&15, m=quad*4+reg (quad 0 holds batches 0..3).

#define BB 2048
#define TT 60
#define DD 6
#define HH 64
#define FF 10
#define NB 4     // batches per block

#define XS 968   // xsp per-batch stride in shorts (60*16 + 8 pad)
#define HS 72    // h split per-batch stride in shorts (144B, 16B-aligned)

typedef short bf16x8 __attribute__((ext_vector_type(8)));
typedef float f32x4  __attribute__((ext_vector_type(4)));

__device__ __forceinline__ unsigned short f2bf(float f) {
    union { float f; unsigned u; } v; v.f = f;
    unsigned r = v.u + 0x7fffu + ((v.u >> 16) & 1u);   // round-to-nearest-even
    return (unsigned short)(r >> 16);
}
__device__ __forceinline__ float bf2f(unsigned short b) {
    union { unsigned u; float f; } v; v.u = ((unsigned)b) << 16; return v.f;
}
__device__ __forceinline__ float hsig_f(float v) {
    return __builtin_amdgcn_fmed3f(fmaf(v, 0.16666666666666666f, 0.5f), 0.0f, 1.0f);
}
__device__ __forceinline__ float tanh_f(float x) {
    float xc = fminf(fmaxf(x, -12.0f), 12.0f);
    float e  = __builtin_amdgcn_exp2f(xc * 2.8853900817779268f); // 2*log2(e)
    return (e - 1.0f) * __builtin_amdgcn_rcpf(e + 1.0f);
}
__device__ __forceinline__ float uni(float v) {
    return __int_as_float(__builtin_amdgcn_readfirstlane(__float_as_int(v)));
}
__device__ __forceinline__ void pinv(bf16x8& v) { asm volatile("" : "+v"(v)); }

__global__ __launch_bounds__(256, 2)
void sfm_kernel(
    const float* __restrict__ x,
    const float* __restrict__ W_i,  const float* __restrict__ U_i,  const float* __restrict__ b_i,
    const float* __restrict__ W_ste,const float* __restrict__ U_ste,const float* __restrict__ b_ste,
    const float* __restrict__ W_fre,const float* __restrict__ U_fre,const float* __restrict__ b_fre,
    const float* __restrict__ W_c,  const float* __restrict__ U_c,  const float* __restrict__ b_c,
    const float* __restrict__ W_o,  const float* __restrict__ U_o,  const float* __restrict__ b_o,
    const float* __restrict__ U_a,  const float* __restrict__ b_a,
    const float* __restrict__ W_p,  const float* __restrict__ b_p,
    float* __restrict__ out)
{
    const int tid  = threadIdx.x;
    const int lane = tid & 63;
    const int wave = tid >> 6;      // == gate id (0=i,1=ste,2=c,3=o)
    const int q    = lane >> 4;     // quad 0..3
    const int n16  = lane & 15;
    const int b0   = blockIdx.x * NB;

    __shared__ __align__(16) unsigned short xsp[NB * XS];   // presplit x
    __shared__ __align__(16) unsigned short hhi[NB * HS];   // h hi-bf16
    __shared__ __align__(16) unsigned short hlo[NB * HS];   // h lo-bf16
    __shared__ __align__(16) float zbuf[4 * 64 * NB];       // z[g][hcol][b]
    __shared__ __align__(16) float frebuf[16 * NB];         // zfre[f][b]
    __shared__ float red[4][NB];

    // ---- stage + pre-split x (one (b,s) record per thread) ----
    for (int item = tid; item < NB * TT; item += 256) {
        const float* xg = x + (size_t)b0 * (TT * DD) + item * DD;
        const int b = item / TT, s = item - b * TT;
        unsigned short* dst = &xsp[b * XS + s * 16];
        #pragma unroll
        for (int d = 0; d < DD; ++d) {
            const float v = xg[d];
            const unsigned short hb = f2bf(v);
            dst[d]     = hb;
            dst[8 + d] = f2bf(v - bf2f(hb));
        }
        dst[6] = 0x3F80; dst[7] = 0;   // bias row: 1.0 exact, lo = 0
        dst[14] = 0; dst[15] = 0;
    }
    for (int i = tid; i < NB * HS; i += 256) { hhi[i] = 0; hlo[i] = 0; }

    // ---- per-wave gate weights ----
    const float* Ug = (wave == 0) ? U_i : (wave == 1) ? U_ste : (wave == 2) ? U_c : U_o;
    const float* Wg = (wave == 0) ? W_i : (wave == 1) ? W_ste : (wave == 2) ? W_c : W_o;
    const float* bg = (wave == 0) ? b_i : (wave == 1) ? b_ste : (wave == 2) ? b_c : b_o;

    // ---- static B-frags: B[k][n], lane holds k = c*32 + q*8 + j, n = n16(+16t) ----
    bf16x8 Bh[5][3], Bl[5][3];
    #pragma unroll
    for (int t = 0; t < 5; ++t) {
        #pragma unroll
        for (int c = 0; c < 3; ++c) {
            #pragma unroll
            for (int j = 0; j < 8; ++j) {
                const int kv = c * 32 + q * 8 + j;   // 0..95 (71..95 zero rows)
                float v = 0.0f;
                if (t < 4) {
                    const int n = t * 16 + n16;
                    if      (kv < 64)  v = Ug[kv * HH + n];
                    else if (kv < 70)  v = Wg[(kv - 64) * HH + n];
                    else if (kv == 70) v = bg[n];
                } else if (wave == 3 && n16 < FF) {
                    if      (kv < 64)  v = U_fre[kv * FF + n16];
                    else if (kv < 70)  v = W_fre[(kv - 64) * FF + n16];
                    else if (kv == 70) v = b_fre[n16];
                }
                const unsigned short hb = f2bf(v);
                Bh[t][c][j] = (short)hb;
                Bl[t][c][j] = (short)f2bf(v - bf2f(hb));
            }
            pinv(Bh[t][c]); pinv(Bl[t][c]);
        }
    }

    // ---- pointwise mapping: batch pb = tid&3, col pc = tid>>2 (0..63) ----
    const int pb = tid & (NB - 1);
    const int pc = tid >> 2;
    const float bav = b_a[pc];
    const float wpv = W_p[pc];
    const float bpv = uni(b_p[0]);
    float uav[FF];
    #pragma unroll
    for (int f = 0; f < FF; ++f) uav[f] = uni(U_a[f]);

    // cos/sin(2*pi*j/10) tables; step s uses index (f*((s+1)%10))%10 -> folded
    const float CT[FF] = { 1.0f,  0.8090169943749475f,  0.30901699437494745f,
                          -0.30901699437494745f, -0.8090169943749475f, -1.0f,
                          -0.8090169943749475f, -0.30901699437494745f,
                           0.30901699437494745f,  0.8090169943749475f };
    const float ST[FF] = { 0.0f,  0.5877852522924731f,  0.9510565162951535f,
                           0.9510565162951535f,  0.5877852522924731f,  0.0f,
                          -0.5877852522924731f, -0.9510565162951535f,
                          -0.9510565162951535f, -0.5877852522924731f };

    float Sre[FF], Sim[FF];
    #pragma unroll
    for (int f = 0; f < FF; ++f) { Sre[f] = 0.0f; Sim[f] = 0.0f; }
    float hv = 0.0f;

    const int ab = n16 & (NB - 1);
    const unsigned short* hhp = &hhi[ab * HS];
    const unsigned short* hlp = &hlo[ab * HS];

    __syncthreads();

    for (int sQ = 0; sQ < 6; ++sQ) {
        const unsigned short* xrow = &xsp[ab * XS + sQ * 160];
        #pragma unroll
        for (int k = 0; k < 10; ++k) {
            // ---- A-frags: pure vector LDS reads of pre-split bf16 ----
            bf16x8 Ah[3], Al[3];
            #pragma unroll
            for (int c = 0; c < 2; ++c) {
                Ah[c] = *(const bf16x8*)&hhp[c * 32 + q * 8];
                Al[c] = *(const bf16x8*)&hlp[c * 32 + q * 8];
            }
            {
                const bf16x8 xvh = *(const bf16x8*)&xrow[k * 16];
                const bf16x8 xvl = *(const bf16x8*)&xrow[k * 16 + 8];
                const bf16x8 zf = {0, 0, 0, 0, 0, 0, 0, 0};
                Ah[2] = (q == 0) ? xvh : zf;
                Al[2] = (q == 0) ? xvl : zf;
            }

            // ---- MFMAs, accumulator-interleaved: consecutive MFMAs hit
            // different accs -> 4-5-way ILP hides ~15cyc dep latency ----
            f32x4 acc0 = {0.f,0.f,0.f,0.f}, acc1 = acc0, acc2 = acc0, acc3 = acc0, acc4 = acc0;
            #pragma unroll
            for (int c = 0; c < 3; ++c) {
                #pragma unroll
                for (int tm = 0; tm < 3; ++tm) {
                    const bf16x8 a = (tm == 0) ? Al[c] : Ah[c];
                    acc0 = __builtin_amdgcn_mfma_f32_16x16x32_bf16(a, (tm==1) ? Bl[0][c] : Bh[0][c], acc0, 0, 0, 0);
                    acc1 = __builtin_amdgcn_mfma_f32_16x16x32_bf16(a, (tm==1) ? Bl[1][c] : Bh[1][c], acc1, 0, 0, 0);
                    acc2 = __builtin_amdgcn_mfma_f32_16x16x32_bf16(a, (tm==1) ? Bl[2][c] : Bh[2][c], acc2, 0, 0, 0);
                    acc3 = __builtin_amdgcn_mfma_f32_16x16x32_bf16(a, (tm==1) ? Bl[3][c] : Bh[3][c], acc3, 0, 0, 0);
                    if (wave == 3)
                        acc4 = __builtin_amdgcn_mfma_f32_16x16x32_bf16(a, (tm==1) ? Bl[4][c] : Bh[4][c], acc4, 0, 0, 0);
                }
            }

            // ---- write z to LDS (quad 0 regs 0..3 = batches 0..3) ----
            if (q == 0) {
                *(f32x4*)&zbuf[(wave * 64 +  0 + n16) * NB] = acc0;
                *(f32x4*)&zbuf[(wave * 64 + 16 + n16) * NB] = acc1;
                *(f32x4*)&zbuf[(wave * 64 + 32 + n16) * NB] = acc2;
                *(f32x4*)&zbuf[(wave * 64 + 48 + n16) * NB] = acc3;
                if (wave == 3 && n16 < FF)
                    *(f32x4*)&frebuf[n16 * NB] = acc4;
            }
            __syncthreads();

            // ---- pointwise: batch pb, col pc ----
            const float zi = zbuf[(0 * 64 + pc) * NB + pb];
            const float zs = zbuf[(1 * 64 + pc) * NB + pb];
            const float zc = zbuf[(2 * 64 + pc) * NB + pb];
            const float zo = zbuf[(3 * 64 + pc) * NB + pb];
            float fr[FF];
            #pragma unroll
            for (int f = 0; f < FF; ++f) fr[f] = hsig_f(frebuf[f * NB + pb]);

            const float iv  = hsig_f(zi);
            const float stv = hsig_f(zs);
            const float ov  = hsig_f(zo);
            const float cv  = iv * tanh_f(zc);

            float aacc = bav;
            #pragma unroll
            for (int f = 0; f < FF; ++f) {
                const int idx = (f * ((k + 1) % 10)) % 10;   // compile-time
                const float fc = stv * fr[f];
                Sre[f] = fmaf(fc, Sre[f], cv * CT[idx]);
                Sim[f] = fmaf(fc, Sim[f], cv * ST[idx]);
                const float A = fmaf(Sim[f], Sim[f], Sre[f] * Sre[f]);
                aacc = fmaf(A, uav[f], aacc);
            }
            hv = ov * tanh_f(aacc);

            // split h -> bf16 hi/lo, write to LDS (the ONLY conversion point)
            {
                const unsigned short hb = f2bf(hv);
                hhi[pb * HS + pc] = hb;
                hlo[pb * HS + pc] = f2bf(hv - bf2f(hb));
            }
            __syncthreads();
        }
    }

    // ---- output: out[b] = sum_col h*W_p + b_p ----
    float val = hv * wpv;
    val += __shfl_xor(val, 4, 64);
    val += __shfl_xor(val, 8, 64);
    val += __shfl_xor(val, 16, 64);
    val += __shfl_xor(val, 32, 64);
    if (lane < NB) red[wave][lane] = val;   // lanes 0..3: batch = lane
    __syncthreads();
    if (tid < NB)
        out[b0 + tid] = red[0][tid] + red[1][tid] + red[2][tid] + red[3][tid] + bpv;
}

extern "C" void kernel_launch(void* const* d_in, const int* in_sizes, int n_in,
                              void* d_out, int out_size, void* d_ws, size_t ws_size,
                              hipStream_t stream) {
    (void)in_sizes; (void)n_in; (void)d_ws; (void)ws_size; (void)out_size;
    const float* x     = (const float*)d_in[0];
    const float* W_i   = (const float*)d_in[1];
    const float* U_i   = (const float*)d_in[2];
    const float* b_i   = (const float*)d_in[3];
    const float* W_ste = (const float*)d_in[4];
    const float* U_ste = (const float*)d_in[5];
    const float* b_ste = (const float*)d_in[6];
    const float* W_fre = (const float*)d_in[7];
    const float* U_fre = (const float*)d_in[8];
    const float* b_fre = (const float*)d_in[9];
    const float* W_c   = (const float*)d_in[10];
    const float* U_c   = (const float*)d_in[11];
    const float* b_c   = (const float*)d_in[12];
    const float* W_o   = (const float*)d_in[13];
    const float* U_o   = (const float*)d_in[14];
    const float* b_o   = (const float*)d_in[15];
    const float* U_a   = (const float*)d_in[16];
    const float* b_a   = (const float*)d_in[17];
    const float* W_p   = (const float*)d_in[18];
    const float* b_p   = (const float*)d_in[19];

    sfm_kernel<<<BB / NB, 256, 0, stream>>>(
        x, W_i, U_i, b_i, W_ste, U_ste, b_ste, W_fre, U_fre, b_fre,
        W_c, U_c, b_c, W_o, U_o, b_o, U_a, b_a, W_p, b_p, (float*)d_out);
}

// Round 8
// 163.694 us; speedup vs baseline: 1.0829x; 1.0193x over previous
//
#include <hip/hip_runtime.h>

// SFM recurrent model via MFMA: B=2048, T=60, D=6, H=64, F=10, O=1.
//
// R1-R3: VALU readlane-GEMV, 183 us (readlane ~1/4 rate).
// R4: 5 GEMVs via mfma_16x16x32_bf16 split-bf16 -> 100 us.
// R5: pre-split bf16 in LDS -> 83 us (NB=8, 1 wave/SIMD, latency-bound).
// R6: NB=4, 2 blk/CU -> 98 us (overlap real, but MFMA/CU doubled).
// R7: acc-interleave + 10x unroll -> 111 us. KEY FINDING: 16x16x32 MFMA
//     occupies the SIMD matrix pipe 16 cyc STRUCTURALLY (512 MAC/cyc/SIMD);
//     interleaving can't reduce it. MFMA efficiency was 6% (m=4/16).
// R8: NB=8 (m=8/16) x 512-thread blocks: 256 blocks, 8 waves, 2 waves/SIMD.
//     Wave w owns gate w>>1, col-half (w&1)*32 (2 n-tiles; wave 7 + fre).
//     MFMA pipe/SIMD/step ~600-720 cyc (half of R7); pointwise exactly
//     1 (batch,col)/thread. Compact loop (no 10x unroll).
//
// MFMA tile: m=batch (8 of 16, 2x mirror), n=hcol, K=96: rows 0..63 h@U,
// 64..69 x@W, 70 bias (A row 70 = 1.0; rows 71..95 zero).
// C layout: n=lane&15, m=quad*4+reg (quads 0,1 = batches 0..7).

#define BB 2048
#define TT 60
#define DD 6
#define HH 64
#define FF 10
#define NB 8     // batches per block

#define XS 968   // xsp per-batch stride in shorts (60*16 + 8 pad)
#define HS 72    // h split per-batch stride in shorts

typedef short bf16x8 __attribute__((ext_vector_type(8)));
typedef float f32x4  __attribute__((ext_vector_type(4)));

__device__ __forceinline__ unsigned short f2bf(float f) {
    union { float f; unsigned u; } v; v.f = f;
    unsigned r = v.u + 0x7fffu + ((v.u >> 16) & 1u);   // round-to-nearest-even
    return (unsigned short)(r >> 16);
}
__device__ __forceinline__ float bf2f(unsigned short b) {
    union { unsigned u; float f; } v; v.u = ((unsigned)b) << 16; return v.f;
}
__device__ __forceinline__ float hsig_f(float v) {
    return __builtin_amdgcn_fmed3f(fmaf(v, 0.16666666666666666f, 0.5f), 0.0f, 1.0f);
}
__device__ __forceinline__ float tanh_f(float x) {
    float xc = fminf(fmaxf(x, -12.0f), 12.0f);
    float e  = __builtin_amdgcn_exp2f(xc * 2.8853900817779268f); // 2*log2(e)
    return (e - 1.0f) * __builtin_amdgcn_rcpf(e + 1.0f);
}
__device__ __forceinline__ float uni(float v) {
    return __int_as_float(__builtin_amdgcn_readfirstlane(__float_as_int(v)));
}
__device__ __forceinline__ void pinv(bf16x8& v) { asm volatile("" : "+v"(v)); }

__global__ __launch_bounds__(512, 2)
void sfm_kernel(
    const float* __restrict__ x,
    const float* __restrict__ W_i,  const float* __restrict__ U_i,  const float* __restrict__ b_i,
    const float* __restrict__ W_ste,const float* __restrict__ U_ste,const float* __restrict__ b_ste,
    const float* __restrict__ W_fre,const float* __restrict__ U_fre,const float* __restrict__ b_fre,
    const float* __restrict__ W_c,  const float* __restrict__ U_c,  const float* __restrict__ b_c,
    const float* __restrict__ W_o,  const float* __restrict__ U_o,  const float* __restrict__ b_o,
    const float* __restrict__ U_a,  const float* __restrict__ b_a,
    const float* __restrict__ W_p,  const float* __restrict__ b_p,
    float* __restrict__ out)
{
    const int tid  = threadIdx.x;
    const int lane = tid & 63;
    const int wave = tid >> 6;      // 0..7
    const int q    = lane >> 4;     // quad 0..3
    const int n16  = lane & 15;
    const int b0   = blockIdx.x * NB;

    __shared__ __align__(16) unsigned short xsp[NB * XS];   // presplit x
    __shared__ __align__(16) unsigned short hhi[NB * HS];   // h hi-bf16
    __shared__ __align__(16) unsigned short hlo[NB * HS];   // h lo-bf16
    __shared__ __align__(16) float zbuf[4 * 64 * NB];       // z[g][hcol][b8]
    __shared__ __align__(16) float frebuf[16 * NB];         // zfre[f][b8]
    __shared__ float red[8][NB];

    // ---- stage + pre-split x (one (b,s) record per thread) ----
    if (tid < NB * TT) {
        const float* xg = x + (size_t)b0 * (TT * DD) + tid * DD;
        const int b = tid / TT, s = tid - b * TT;
        unsigned short* dst = &xsp[b * XS + s * 16];
        #pragma unroll
        for (int d = 0; d < DD; ++d) {
            const float v = xg[d];
            const unsigned short hb = f2bf(v);
            dst[d]     = hb;
            dst[8 + d] = f2bf(v - bf2f(hb));
        }
        dst[6] = 0x3F80; dst[7] = 0;   // bias row: 1.0 exact, lo = 0
        dst[14] = 0; dst[15] = 0;
    }
    for (int i = tid; i < NB * HS; i += 512) { hhi[i] = 0; hlo[i] = 0; }

    // ---- per-wave weights: gate g = wave>>1, cols colbase..colbase+31 ----
    const int g = wave >> 1;
    const int colbase = (wave & 1) * 32;
    const float* Ug = (g == 0) ? U_i : (g == 1) ? U_ste : (g == 2) ? U_c : U_o;
    const float* Wg = (g == 0) ? W_i : (g == 1) ? W_ste : (g == 2) ? W_c : W_o;
    const float* bg = (g == 0) ? b_i : (g == 1) ? b_ste : (g == 2) ? b_c : b_o;

    // ---- static B-frags: B[k][n], lane k = c*32+q*8+j; t=0,1 gate tiles,
    //      t=2 (wave 7 only) = fre tile ----
    bf16x8 Bh[3][3], Bl[3][3];
    #pragma unroll
    for (int t = 0; t < 3; ++t) {
        #pragma unroll
        for (int c = 0; c < 3; ++c) {
            #pragma unroll
            for (int j = 0; j < 8; ++j) {
                const int kv = c * 32 + q * 8 + j;   // 0..95
                float v = 0.0f;
                if (t < 2) {
                    const int n = colbase + t * 16 + n16;
                    if      (kv < 64)  v = Ug[kv * HH + n];
                    else if (kv < 70)  v = Wg[(kv - 64) * HH + n];
                    else if (kv == 70) v = bg[n];
                } else if (wave == 7 && n16 < FF) {
                    if      (kv < 64)  v = U_fre[kv * FF + n16];
                    else if (kv < 70)  v = W_fre[(kv - 64) * FF + n16];
                    else if (kv == 70) v = b_fre[n16];
                }
                const unsigned short hb = f2bf(v);
                Bh[t][c][j] = (short)hb;
                Bl[t][c][j] = (short)f2bf(v - bf2f(hb));
            }
            pinv(Bh[t][c]); pinv(Bl[t][c]);
        }
    }

    // ---- pointwise mapping: batch pb = tid&7, col pc = tid>>3 (0..63) ----
    const int pb = tid & (NB - 1);
    const int pc = tid >> 3;
    const float bav = b_a[pc];
    const float wpv = W_p[pc];
    const float bpv = uni(b_p[0]);
    float uav[FF];
    #pragma unroll
    for (int f = 0; f < FF; ++f) uav[f] = uni(U_a[f]);

    // ---- rotation constants: cos/sin(2*pi*f/10), exact, period-10 reset ----
    const float CBt[FF] = { 1.0f,  0.8090169943749475f,  0.30901699437494745f,
                           -0.30901699437494745f, -0.8090169943749475f, -1.0f,
                           -0.8090169943749475f, -0.30901699437494745f,
                            0.30901699437494745f,  0.8090169943749475f };
    const float SBt[FF] = { 0.0f,  0.5877852522924731f,  0.9510565162951535f,
                            0.9510565162951535f,  0.5877852522924731f,  0.0f,
                           -0.5877852522924731f, -0.9510565162951535f,
                           -0.9510565162951535f, -0.5877852522924731f };

    float Sre[FF], Sim[FF], cs[FF], sn[FF];
    #pragma unroll
    for (int f = 0; f < FF; ++f) {
        Sre[f] = 0.0f; Sim[f] = 0.0f; cs[f] = CBt[f]; sn[f] = SBt[f];
    }
    float hv = 0.0f;

    const int ab = n16 & (NB - 1);
    const unsigned short* hhp = &hhi[ab * HS];
    const unsigned short* hlp = &hlo[ab * HS];
    const unsigned short* xrow = &xsp[ab * XS];

    __syncthreads();

    int sm = 0;
    for (int s = 0; s < TT; ++s) {
        // ---- A-frags: pure vector LDS reads of pre-split bf16 ----
        bf16x8 Ah[3], Al[3];
        #pragma unroll
        for (int c = 0; c < 2; ++c) {
            Ah[c] = *(const bf16x8*)&hhp[c * 32 + q * 8];
            Al[c] = *(const bf16x8*)&hlp[c * 32 + q * 8];
        }
        {
            const bf16x8 xvh = *(const bf16x8*)&xrow[s * 16];
            const bf16x8 xvl = *(const bf16x8*)&xrow[s * 16 + 8];
            const bf16x8 zf = {0, 0, 0, 0, 0, 0, 0, 0};
            Ah[2] = (q == 0) ? xvh : zf;
            Al[2] = (q == 0) ? xvl : zf;
        }

        // ---- MFMAs: 2 gate tiles (+fre on wave 7), 3-term split ----
        f32x4 acc0 = {0.f,0.f,0.f,0.f}, acc1 = acc0, acc2 = acc0;
        #pragma unroll
        for (int c = 0; c < 3; ++c) {
            #pragma unroll
            for (int tm = 0; tm < 3; ++tm) {
                const bf16x8 a = (tm == 0) ? Al[c] : Ah[c];
                acc0 = __builtin_amdgcn_mfma_f32_16x16x32_bf16(a, (tm==1) ? Bl[0][c] : Bh[0][c], acc0, 0, 0, 0);
                acc1 = __builtin_amdgcn_mfma_f32_16x16x32_bf16(a, (tm==1) ? Bl[1][c] : Bh[1][c], acc1, 0, 0, 0);
                if (wave == 7)
                    acc2 = __builtin_amdgcn_mfma_f32_16x16x32_bf16(a, (tm==1) ? Bl[2][c] : Bh[2][c], acc2, 0, 0, 0);
            }
        }

        // ---- write z (quads 0,1 hold batches 0..7) ----
        if (q < 2) {
            const int base = (g * 64 + colbase + n16) * NB + q * 4;
            *(f32x4*)&zbuf[base]          = acc0;
            *(f32x4*)&zbuf[base + 16*NB]  = acc1;
            if (wave == 7)
                *(f32x4*)&frebuf[n16 * NB + q * 4] = acc2;
        }
        __syncthreads();

        // ---- pointwise: batch pb, col pc ----
        const float zi = zbuf[(0 * 64 + pc) * NB + pb];
        const float zs = zbuf[(1 * 64 + pc) * NB + pb];
        const float zc = zbuf[(2 * 64 + pc) * NB + pb];
        const float zo = zbuf[(3 * 64 + pc) * NB + pb];
        float fr[FF];
        #pragma unroll
        for (int f = 0; f < FF; ++f) fr[f] = hsig_f(frebuf[f * NB + pb]);

        const float iv  = hsig_f(zi);
        const float stv = hsig_f(zs);
        const float ov  = hsig_f(zo);
        const float cv  = iv * tanh_f(zc);

        if (sm == 0) {
            #pragma unroll
            for (int f = 0; f < FF; ++f) { cs[f] = CBt[f]; sn[f] = SBt[f]; }
        }

        float aacc = bav;
        #pragma unroll
        for (int f = 0; f < FF; ++f) {
            const float fc = stv * fr[f];
            Sre[f] = fmaf(fc, Sre[f], cv * cs[f]);
            Sim[f] = fmaf(fc, Sim[f], cv * sn[f]);
            const float A = fmaf(Sim[f], Sim[f], Sre[f] * Sre[f]);
            aacc = fmaf(A, uav[f], aacc);
            const float cc = cs[f];
            cs[f] = fmaf(cc, CBt[f], -(sn[f] * SBt[f]));
            sn[f] = fmaf(cc, SBt[f],   sn[f] * CBt[f]);
        }
        hv = ov * tanh_f(aacc);

        // split h -> bf16 hi/lo, write to LDS (the ONLY conversion point)
        {
            const unsigned short hb = f2bf(hv);
            hhi[pb * HS + pc] = hb;
            hlo[pb * HS + pc] = f2bf(hv - bf2f(hb));
        }
        if (++sm == 10) sm = 0;
        __syncthreads();
    }

    // ---- output: out[b] = sum_col h*W_p + b_p ----
    // wave w: pc = w*8 + (lane>>3), pb = lane&7.
    float val = hv * wpv;
    val += __shfl_xor(val, 8, 64);
    val += __shfl_xor(val, 16, 64);
    val += __shfl_xor(val, 32, 64);
    if (lane < NB) red[wave][lane] = val;   // lanes 0..7: batch = lane
    __syncthreads();
    if (tid < NB) {
        float acc = bpv;
        #pragma unroll
        for (int w = 0; w < 8; ++w) acc += red[w][tid];
        out[b0 + tid] = acc;
    }
}

extern "C" void kernel_launch(void* const* d_in, const int* in_sizes, int n_in,
                              void* d_out, int out_size, void* d_ws, size_t ws_size,
                              hipStream_t stream) {
    (void)in_sizes; (void)n_in; (void)d_ws; (void)ws_size; (void)out_size;
    const float* x     = (const float*)d_in[0];
    const float* W_i   = (const float*)d_in[1];
    const float* U_i   = (const float*)d_in[2];
    const float* b_i   = (const float*)d_in[3];
    const float* W_ste = (const float*)d_in[4];
    const float* U_ste = (const float*)d_in[5];
    const float* b_ste = (const float*)d_in[6];
    const float* W_fre = (const float*)d_in[7];
    const float* U_fre = (const float*)d_in[8];
    const float* b_fre = (const float*)d_in[9];
    const float* W_c   = (const float*)d_in[10];
    const float* U_c   = (const float*)d_in[11];
    const float* b_c   = (const float*)d_in[12];
    const float* W_o   = (const float*)d_in[13];
    const float* U_o   = (const float*)d_in[14];
    const float* b_o   = (const float*)d_in[15];
    const float* U_a   = (const float*)d_in[16];
    const float* b_a   = (const float*)d_in[17];
    const float* W_p   = (const float*)d_in[18];
    const float* b_p   = (const float*)d_in[19];

    sfm_kernel<<<BB / NB, 512, 0, stream>>>(
        x, W_i, U_i, b_i, W_ste, U_ste, b_ste, W_fre, U_fre, b_fre,
        W_c, U_c, b_c, W_o, U_o, b_o, U_a, b_a, W_p, b_p, (float*)d_out);
}

// Round 9
// 159.089 us; speedup vs baseline: 1.1143x; 1.0289x over previous
//
#include <hip/hip_runtime.h>

// SFM recurrent model via MFMA: B=2048, T=60, D=6, H=64, F=10, O=1.
//
// R1-R3: VALU readlane-GEMV, 183 us. R4: MFMA split-bf16 -> 100 us.
// R5: pre-split bf16 in LDS -> 83 us (1 blk/CU: M/P phases serial).
// R6: NB=4, 2 blk/CU -> 98 us (slide works, MFMA doubled).
// R7: 16 cyc/MFMA is structural -> interleave useless. R8: NB=8 -> 86 us,
//     1 blk/CU serial again, 30% idle.
// R9: NB=4 + 2 blk/CU (slide) + LEAN MFMA: k=64 exactly (x@W + bias
//     REMOVED from MFMA -> 17 tiles x 6 = 102 MFMA/block, -33%).
//     x@W+bias -> pointwise fma chain (fp32, exact). fre x-part
//     precomputed xf[b][s][f] at init, added by fre wave pre-write.
//     Rotation -> period-10 LDS table. frebuf transposed for b128 reads.
//
// MFMA tile: m=batch (4 of 16), n=hcol, K=64 (pure h@U, 2 chunks).
// Wave w owns gate w cols 0..47 (3 tiles) + 4th tile: w0,1,2: own col
// 48..63; wave3: fre tile; wave0 extra: gate3 col 48..63 (5 tiles).
// C layout: n=lane&15, m=quad*4+reg (quad 0 = batches 0..3).

#define BB 2048
#define TT 60
#define DD 6
#define HH 64
#define FF 10
#define NB 4      // batches per block

#define HS 72     // h split per-batch stride in shorts
#define XCS 964   // xc per-batch stride in floats (60*16 + 4 pad -> bank spread)

typedef short bf16x8 __attribute__((ext_vector_type(8)));
typedef float f32x4  __attribute__((ext_vector_type(4)));

__device__ __forceinline__ unsigned short f2bf(float f) {
    union { float f; unsigned u; } v; v.f = f;
    unsigned r = v.u + 0x7fffu + ((v.u >> 16) & 1u);   // RNE
    return (unsigned short)(r >> 16);
}
__device__ __forceinline__ float bf2f(unsigned short b) {
    union { unsigned u; float f; } v; v.u = ((unsigned)b) << 16; return v.f;
}
__device__ __forceinline__ float hsig_f(float v) {
    return __builtin_amdgcn_fmed3f(fmaf(v, 0.16666666666666666f, 0.5f), 0.0f, 1.0f);
}
__device__ __forceinline__ float tanh_f(float x) {
    float xc = fminf(fmaxf(x, -12.0f), 12.0f);
    float e  = __builtin_amdgcn_exp2f(xc * 2.8853900817779268f); // 2*log2(e)
    return (e - 1.0f) * __builtin_amdgcn_rcpf(e + 1.0f);
}
__device__ __forceinline__ float uni(float v) {
    return __int_as_float(__builtin_amdgcn_readfirstlane(__float_as_int(v)));
}
__device__ __forceinline__ void pinv(bf16x8& v) { asm volatile("" : "+v"(v)); }

__global__ __launch_bounds__(256, 2)
void sfm_kernel(
    const float* __restrict__ x,
    const float* __restrict__ W_i,  const float* __restrict__ U_i,  const float* __restrict__ b_i,
    const float* __restrict__ W_ste,const float* __restrict__ U_ste,const float* __restrict__ b_ste,
    const float* __restrict__ W_fre,const float* __restrict__ U_fre,const float* __restrict__ b_fre,
    const float* __restrict__ W_c,  const float* __restrict__ U_c,  const float* __restrict__ b_c,
    const float* __restrict__ W_o,  const float* __restrict__ U_o,  const float* __restrict__ b_o,
    const float* __restrict__ U_a,  const float* __restrict__ b_a,
    const float* __restrict__ W_p,  const float* __restrict__ b_p,
    float* __restrict__ out)
{
    const int tid  = threadIdx.x;
    const int lane = tid & 63;
    const int wave = tid >> 6;      // 0..3
    const int q    = lane >> 4;     // quad 0..3
    const int n16  = lane & 15;
    const int b0   = blockIdx.x * NB;

    __shared__ __align__(16) float xc[NB * XCS];           // [b][s][0..5]=x fp32, [6..15]=xf (fre-x + b_fre)
    __shared__ __align__(16) unsigned short hhi[NB * HS];  // h hi-bf16
    __shared__ __align__(16) unsigned short hlo[NB * HS];  // h lo-bf16
    __shared__ __align__(16) float zbuf[4 * 64 * NB];      // z[g][hcol][b]  (pure h@U)
    __shared__ __align__(16) float frebuf[NB * 12];        // zfre[b][f] transposed, +xf folded
    __shared__ __align__(16) float ctab[10 * 10 * 2];      // [m][f] -> (cos,sin), m=(s+1)%10
    __shared__ float cstabB[10 * 2];
    __shared__ float red[4][NB];

    // ---- init phase 1: stage x fp32 (coalesced), base trig table, zero h ----
    for (int i = tid; i < NB * TT * DD; i += 256) {
        const int b = i / (TT * DD), rem = i - b * (TT * DD);
        const int s = rem / DD, d = rem - s * DD;
        xc[b * XCS + s * 16 + d] = x[(size_t)b0 * (TT * DD) + i];
    }
    if (tid < 10) {
        // cos/sin(2*pi*j/10), exact constants; per-j compare folds to immediates
        const float CTc[10] = { 1.0f,  0.8090169943749475f,  0.30901699437494745f,
                               -0.30901699437494745f, -0.8090169943749475f, -1.0f,
                               -0.8090169943749475f, -0.30901699437494745f,
                                0.30901699437494745f,  0.8090169943749475f };
        const float STc[10] = { 0.0f,  0.5877852522924731f,  0.9510565162951535f,
                                0.9510565162951535f,  0.5877852522924731f,  0.0f,
                               -0.5877852522924731f, -0.9510565162951535f,
                               -0.9510565162951535f, -0.5877852522924731f };
        float cc = 0.0f, ss = 0.0f;
        #pragma unroll
        for (int j = 0; j < 10; ++j) if (tid == j) { cc = CTc[j]; ss = STc[j]; }
        cstabB[tid * 2] = cc; cstabB[tid * 2 + 1] = ss;
    }
    for (int i = tid; i < NB * HS; i += 256) { hhi[i] = 0; hlo[i] = 0; }
    __syncthreads();

    // ---- init phase 2: xf[b][s][f] = b_fre[f] + sum_d x*W_fre, full ctab ----
    if (tid < NB * TT) {
        const int b = tid / TT, s = tid - b * TT;
        float xr[DD];
        #pragma unroll
        for (int d = 0; d < DD; ++d) xr[d] = xc[b * XCS + s * 16 + d];
        #pragma unroll
        for (int f = 0; f < FF; ++f) {
            float v = b_fre[f];
            #pragma unroll
            for (int d = 0; d < DD; ++d) v = fmaf(xr[d], W_fre[d * FF + f], v);
            xc[b * XCS + s * 16 + 6 + f] = v;
        }
    }
    if (tid < 100) {
        const int mm = tid / 10, ff = tid - mm * 10;
        const int idx = (ff * mm) % 10;
        ctab[tid * 2]     = cstabB[idx * 2];
        ctab[tid * 2 + 1] = cstabB[idx * 2 + 1];
    }

    // ---- B-frags: tile list per wave (k=64: rows = h only) ----
    // t0..t2: gate=wave, cols 0/16/32. t3: wave3 -> fre, else gate=wave col48.
    // t4 (wave0 only): gate3 col48.
    const int NT = (wave == 0) ? 5 : 4;
    bf16x8 Bh[5][2], Bl[5][2];
    #pragma unroll
    for (int t = 0; t < 5; ++t) {
        if (t >= NT) continue;
        const bool isfre = (t == 3 && wave == 3);
        const int g  = (t == 4) ? 3 : wave;
        const int cb = (t == 3 || t == 4) ? 48 : t * 16;
        const float* Up = isfre ? U_fre :
                          (g == 0) ? U_i : (g == 1) ? U_ste : (g == 2) ? U_c : U_o;
        #pragma unroll
        for (int c = 0; c < 2; ++c) {
            #pragma unroll
            for (int j = 0; j < 8; ++j) {
                const int kv = c * 32 + q * 8 + j;   // 0..63, all real
                float v;
                if (isfre) v = (n16 < FF) ? Up[kv * FF + n16] : 0.0f;
                else       v = Up[kv * HH + cb + n16];
                const unsigned short hb = f2bf(v);
                Bh[t][c][j] = (short)hb;
                Bl[t][c][j] = (short)f2bf(v - bf2f(hb));
            }
            pinv(Bh[t][c]); pinv(Bl[t][c]);
        }
    }

    // ---- pointwise consts: batch pb = tid&3, col pc = tid>>2 ----
    const int pb = tid & (NB - 1);
    const int pc = tid >> 2;
    const float bav = b_a[pc];
    const float wpv = W_p[pc];
    const float bpv = uni(b_p[0]);
    float uav[FF];
    #pragma unroll
    for (int f = 0; f < FF; ++f) uav[f] = uni(U_a[f]);
    // per-col x-weights + biases for the 4 gates (x@W+bias now in VALU)
    float wxi[DD], wxs[DD], wxc[DD], wxo[DD];
    #pragma unroll
    for (int d = 0; d < DD; ++d) {
        wxi[d] = W_i[d * HH + pc];  wxs[d] = W_ste[d * HH + pc];
        wxc[d] = W_c[d * HH + pc];  wxo[d] = W_o[d * HH + pc];
    }
    const float bi = b_i[pc], bs = b_ste[pc], bc = b_c[pc], bo = b_o[pc];

    float Sre[FF], Sim[FF];
    #pragma unroll
    for (int f = 0; f < FF; ++f) { Sre[f] = 0.0f; Sim[f] = 0.0f; }
    float hv = 0.0f;

    const int ab = n16 & (NB - 1);
    const unsigned short* hhp = &hhi[ab * HS];
    const unsigned short* hlp = &hlo[ab * HS];

    __syncthreads();

    int m = 1;  // (s+1) % 10
    for (int s = 0; s < TT; ++s) {
        // ---- A-frags: 4 x ds_read_b128 of pre-split h ----
        bf16x8 Ah[2], Al[2];
        #pragma unroll
        for (int c = 0; c < 2; ++c) {
            Ah[c] = *(const bf16x8*)&hhp[c * 32 + q * 8];
            Al[c] = *(const bf16x8*)&hlp[c * 32 + q * 8];
        }

        // ---- MFMAs: per tile 2 chunks x 3 terms = 6 ----
        f32x4 acc[5];
        #pragma unroll
        for (int t = 0; t < 5; ++t) {
            if (t >= NT) continue;
            f32x4 a = {0.0f, 0.0f, 0.0f, 0.0f};
            #pragma unroll
            for (int c = 0; c < 2; ++c) {
                a = __builtin_amdgcn_mfma_f32_16x16x32_bf16(Al[c], Bh[t][c], a, 0, 0, 0);
                a = __builtin_amdgcn_mfma_f32_16x16x32_bf16(Ah[c], Bl[t][c], a, 0, 0, 0);
                a = __builtin_amdgcn_mfma_f32_16x16x32_bf16(Ah[c], Bh[t][c], a, 0, 0, 0);
            }
            acc[t] = a;
        }

        // ---- write z (quad 0 regs 0..3 = batches 0..3) ----
        if (q == 0) {
            *(f32x4*)&zbuf[(wave * 64 +  0 + n16) * NB] = acc[0];
            *(f32x4*)&zbuf[(wave * 64 + 16 + n16) * NB] = acc[1];
            *(f32x4*)&zbuf[(wave * 64 + 32 + n16) * NB] = acc[2];
            if (wave == 3) {
                if (n16 < FF) {   // fre: add precomputed x-part, transpose-write
                    #pragma unroll
                    for (int r = 0; r < 4; ++r)
                        frebuf[r * 12 + n16] = acc[3][r] + xc[r * XCS + s * 16 + 6 + n16];
                }
            } else {
                *(f32x4*)&zbuf[(wave * 64 + 48 + n16) * NB] = acc[3];
            }
            if (wave == 0)
                *(f32x4*)&zbuf[(3 * 64 + 48 + n16) * NB] = acc[4];
        }
        __syncthreads();

        // ---- pointwise: batch pb, col pc ----
        const float4 xv4 = *(const float4*)&xc[pb * XCS + s * 16];
        const float2 xv2 = *(const float2*)&xc[pb * XCS + s * 16 + 4];
        const float xa[DD] = {xv4.x, xv4.y, xv4.z, xv4.w, xv2.x, xv2.y};

        float vi = bi, vs = bs, vc = bc, vo = bo;
        #pragma unroll
        for (int d = 0; d < DD; ++d) {
            vi = fmaf(xa[d], wxi[d], vi);
            vs = fmaf(xa[d], wxs[d], vs);
            vc = fmaf(xa[d], wxc[d], vc);
            vo = fmaf(xa[d], wxo[d], vo);
        }
        const float zi = zbuf[(0 * 64 + pc) * NB + pb] + vi;
        const float zs = zbuf[(1 * 64 + pc) * NB + pb] + vs;
        const float zc = zbuf[(2 * 64 + pc) * NB + pb] + vc;
        const float zo = zbuf[(3 * 64 + pc) * NB + pb] + vo;

        const f32x4 fb0 = *(const f32x4*)&frebuf[pb * 12];
        const f32x4 fb1 = *(const f32x4*)&frebuf[pb * 12 + 4];
        const f32x4 fb2 = *(const f32x4*)&frebuf[pb * 12 + 8];
        float fr[FF];
        #pragma unroll
        for (int f = 0; f < 4; ++f) fr[f] = hsig_f(fb0[f]);
        #pragma unroll
        for (int f = 0; f < 4; ++f) fr[4 + f] = hsig_f(fb1[f]);
        fr[8] = hsig_f(fb2[0]); fr[9] = hsig_f(fb2[1]);

        const float iv  = hsig_f(zi);
        const float stv = hsig_f(zs);
        const float ov  = hsig_f(zo);
        const float cv  = iv * tanh_f(zc);

        const float* tp = &ctab[m * 20];
        float aacc = bav;
        #pragma unroll
        for (int f = 0; f < FF; ++f) {
            const float2 tv = *(const float2*)&tp[f * 2];
            const float fc = stv * fr[f];
            Sre[f] = fmaf(fc, Sre[f], cv * tv.x);
            Sim[f] = fmaf(fc, Sim[f], cv * tv.y);
            const float A = fmaf(Sim[f], Sim[f], Sre[f] * Sre[f]);
            aacc = fmaf(A, uav[f], aacc);
        }
        hv = ov * tanh_f(aacc);

        // split h -> bf16 hi/lo, write to LDS (the ONLY conversion point)
        {
            const unsigned short hb = f2bf(hv);
            hhi[pb * HS + pc] = hb;
            hlo[pb * HS + pc] = f2bf(hv - bf2f(hb));
        }
        if (++m == 10) m = 0;
        __syncthreads();
    }

    // ---- output: out[b] = sum_col h*W_p + b_p ----
    float val = hv * wpv;
    val += __shfl_xor(val, 4, 64);
    val += __shfl_xor(val, 8, 64);
    val += __shfl_xor(val, 16, 64);
    val += __shfl_xor(val, 32, 64);
    if (lane < NB) red[wave][lane] = val;
    __syncthreads();
    if (tid < NB)
        out[b0 + tid] = red[0][tid] + red[1][tid] + red[2][tid] + red[3][tid] + bpv;
}

extern "C" void kernel_launch(void* const* d_in, const int* in_sizes, int n_in,
                              void* d_out, int out_size, void* d_ws, size_t ws_size,
                              hipStream_t stream) {
    (void)in_sizes; (void)n_in; (void)d_ws; (void)ws_size; (void)out_size;
    const float* x     = (const float*)d_in[0];
    const float* W_i   = (const float*)d_in[1];
    const float* U_i   = (const float*)d_in[2];
    const float* b_i   = (const float*)d_in[3];
    const float* W_ste = (const float*)d_in[4];
    const float* U_ste = (const float*)d_in[5];
    const float* b_ste = (const float*)d_in[6];
    const float* W_fre = (const float*)d_in[7];
    const float* U_fre = (const float*)d_in[8];
    const float* b_fre = (const float*)d_in[9];
    const float* W_c   = (const float*)d_in[10];
    const float* U_c   = (const float*)d_in[11];
    const float* b_c   = (const float*)d_in[12];
    const float* W_o   = (const float*)d_in[13];
    const float* U_o   = (const float*)d_in[14];
    const float* b_o   = (const float*)d_in[15];
    const float* U_a   = (const float*)d_in[16];
    const float* b_a   = (const float*)d_in[17];
    const float* W_p   = (const float*)d_in[18];
    const float* b_p   = (const float*)d_in[19];

    sfm_kernel<<<BB / NB, 256, 0, stream>>>(
        x, W_i, U_i, b_i, W_ste, U_ste, b_ste, W_fre, U_fre, b_fre,
        W_c, U_c, b_c, W_o, U_o, b_o, U_a, b_a, W_p, b_p, (float*)d_out);
}